// Round 2
// baseline (4766.093 us; speedup 1.0000x reference)
//
#include <hip/hip_runtime.h>
#include <hip/hip_bf16.h>
#include <math.h>

// Problem constants (fixed instance: B=1, Z=8, H=96, W=192, C=256)
#define L_TOK   147456      // Z*H*W
#define CDIM    256
#define C3      768
#define HID     1024
#define NWIN    1024        // 4*16*16
#define NTOK    144         // 2*6*12
#define NHEADS  8
#define HD      32
#define SCALE   0.1767766952966369f   // 1/sqrt(32)

// ---------------------------------------------------------------------------
// LN (+ optional shift & window partition gather). One wave per token row.
// SHIFTWIN=true : local out row t <- LN(x[src(row0+t)]) (roll+partition gather)
// SHIFTWIN=false: local out row t <- LN(x[row0+t])
// ---------------------------------------------------------------------------
template<bool SHIFTWIN>
__global__ __launch_bounds__(256) void ln_kernel(const float* __restrict__ x,
                                                 const float* __restrict__ g,
                                                 const float* __restrict__ b,
                                                 float* __restrict__ out,
                                                 int row0)
{
    const int wave = threadIdx.x >> 6;
    const int lane = threadIdx.x & 63;
    const int t = blockIdx.x * 4 + wave;          // local output row
    int src;
    if constexpr (SHIFTWIN) {
        const int gt  = row0 + t;                 // global window-order row
        const int win = gt / NTOK;
        const int nt  = gt - win * NTOK;
        const int wz = win >> 8, wh = (win >> 4) & 15, ww = win & 15;
        const int lz = nt / 72;
        const int t2 = nt - lz * 72;
        const int lh = t2 / 12, lw = t2 - lh * 12;
        const int z = (wz * 2 + lz + 1) & 7;
        int h = wh * 6 + lh + 3;  if (h >= 96)  h -= 96;
        int w = ww * 12 + lw + 6; if (w >= 192) w -= 192;
        src = (z * 96 + h) * 192 + w;
    } else {
        src = row0 + t;
    }
    const float4 xv = *(const float4*)(x + (size_t)src * CDIM + lane * 4);
    float s  = xv.x + xv.y + xv.z + xv.w;
    float ss = xv.x*xv.x + xv.y*xv.y + xv.z*xv.z + xv.w*xv.w;
    #pragma unroll
    for (int off = 32; off; off >>= 1) {
        s  += __shfl_xor(s,  off);
        ss += __shfl_xor(ss, off);
    }
    const float mean = s * (1.0f / CDIM);
    const float var  = ss * (1.0f / CDIM) - mean * mean;
    const float rstd = rsqrtf(var + 1e-5f);
    const float4 gv = *(const float4*)(g + lane * 4);
    const float4 bv = *(const float4*)(b + lane * 4);
    float4 ov;
    ov.x = (xv.x - mean) * rstd * gv.x + bv.x;
    ov.y = (xv.y - mean) * rstd * gv.y + bv.y;
    ov.z = (xv.z - mean) * rstd * gv.z + bv.z;
    ov.w = (xv.w - mean) * rstd * gv.w + bv.w;
    *(float4*)(out + (size_t)t * CDIM + lane * 4) = ov;
}

// ---------------------------------------------------------------------------
// Relative-position bias gather: bb[h][i][j] = table[posidx(i,j)][wti][h]
// ---------------------------------------------------------------------------
__global__ __launch_bounds__(256) void bias_pre_kernel(const float* __restrict__ bt,
                                                       const int* __restrict__ wti_p,
                                                       float* __restrict__ bb)
{
    const int e = blockIdx.x * 256 + threadIdx.x;        // < 8*144*144
    const int wti = *wti_p;
    const int h  = e / (NTOK * NTOK);
    const int ij = e - h * (NTOK * NTOK);
    const int i = ij / NTOK, j = ij - (ij / NTOK) * NTOK;
    const int zi = i / 72, ri = i - zi * 72, hi = ri / 12, wi = ri - (ri / 12) * 12;
    const int zj = j / 72, rj = j - zj * 72, hj = rj / 12, wj = rj - (rj / 12) * 12;
    const int idx = (zi + 2 * zj) * 828 + (hi + 6 * hj) * 23 + (wi - wj + 11);
    bb[e] = bt[((size_t)idx * 64 + wti) * 8 + h];
}

// ---------------------------------------------------------------------------
// Attention: one block per (local window, head). 192 threads; threads 0..143
// own one query row each; K/V staged in LDS; S row fully in registers.
// qkv layout (chunk-local): [(winl*3+sel)*8+head][144][32]
// out layout (chunk-local): [winl*144+n][head*32+d]
// ---------------------------------------------------------------------------
__global__ __launch_bounds__(192, 1) void attn_kernel(const float* __restrict__ qkv,
                                                      const float* __restrict__ bb,
                                                      float* __restrict__ outb,
                                                      int win0)
{
    __shared__ float ksh[NTOK * HD];
    __shared__ float vsh[NTOK * HD];
    __shared__ int   regs_s[NTOK];

    const int winl = blockIdx.x >> 3;
    const int win  = win0 + winl;                 // global window id
    const int head = blockIdx.x & 7;
    const int tid  = threadIdx.x;

    const float* qb = qkv + (((size_t)(winl * 3 + 0) * 8 + head) * NTOK) * HD;
    const float* kb = qkv + (((size_t)(winl * 3 + 1) * 8 + head) * NTOK) * HD;
    const float* vb = qkv + (((size_t)(winl * 3 + 2) * 8 + head) * NTOK) * HD;

    for (int i = tid; i < NTOK * HD / 4; i += 192) {
        ((float4*)ksh)[i] = ((const float4*)kb)[i];
        ((float4*)vsh)[i] = ((const float4*)vb)[i];
    }
    if (tid < NTOK) {
        const int lz = tid / 72;
        const int t2 = tid - lz * 72;
        const int lh = t2 / 12, lw = t2 - lh * 12;
        const int wz = win >> 8, wh = (win >> 4) & 15, ww = win & 15;
        const int rz = (wz < 3)  ? 0 : (lz == 0 ? 1 : 2);
        const int rh = (wh < 15) ? 0 : (lh < 3  ? 1 : 2);
        const int rw = (ww < 15) ? 0 : (lw < 6  ? 1 : 2);
        regs_s[tid] = rz * 9 + rh * 3 + rw;
    }
    __syncthreads();

    if (tid < NTOK) {
        const int r = tid;
        float q[HD];
        #pragma unroll
        for (int c4 = 0; c4 < HD / 4; ++c4) {
            const float4 v = *(const float4*)(qb + (size_t)r * HD + c4 * 4);
            q[c4*4+0] = v.x * SCALE; q[c4*4+1] = v.y * SCALE;
            q[c4*4+2] = v.z * SCALE; q[c4*4+3] = v.w * SCALE;
        }
        const int myreg = regs_s[r];
        const float* bb_row = bb + (size_t)head * (NTOK * NTOK) + (size_t)r * NTOK;

        float s_arr[NTOK];
        #pragma unroll
        for (int j = 0; j < NTOK; ++j) {
            float acc = 0.0f;
            #pragma unroll
            for (int c4 = 0; c4 < HD / 4; ++c4) {
                const float4 kv = *(const float4*)&ksh[j * HD + c4 * 4];
                acc += q[c4*4+0]*kv.x + q[c4*4+1]*kv.y + q[c4*4+2]*kv.z + q[c4*4+3]*kv.w;
            }
            const float m = (regs_s[j] == myreg) ? 0.0f : -100.0f;
            s_arr[j] = acc + bb_row[j] + m;
        }
        float mx = s_arr[0];
        #pragma unroll
        for (int j = 1; j < NTOK; ++j) mx = fmaxf(mx, s_arr[j]);
        float sum = 0.0f;
        #pragma unroll
        for (int j = 0; j < NTOK; ++j) { const float e = __expf(s_arr[j] - mx); s_arr[j] = e; sum += e; }
        const float inv = 1.0f / sum;

        float o[HD];
        #pragma unroll
        for (int d = 0; d < HD; ++d) o[d] = 0.0f;
        #pragma unroll
        for (int j = 0; j < NTOK; ++j) {
            const float p = s_arr[j];
            #pragma unroll
            for (int c4 = 0; c4 < HD / 4; ++c4) {
                const float4 vv = *(const float4*)&vsh[j * HD + c4 * 4];
                o[c4*4+0] += p * vv.x; o[c4*4+1] += p * vv.y;
                o[c4*4+2] += p * vv.z; o[c4*4+3] += p * vv.w;
            }
        }
        const size_t obase = ((size_t)winl * NTOK + r) * CDIM + head * HD;
        #pragma unroll
        for (int c4 = 0; c4 < HD / 4; ++c4) {
            float4 ov;
            ov.x = o[c4*4+0] * inv; ov.y = o[c4*4+1] * inv;
            ov.z = o[c4*4+2] * inv; ov.w = o[c4*4+3] * inv;
            *(float4*)(outb + obase + c4 * 4) = ov;
        }
    }
}

// ---------------------------------------------------------------------------
// fp32 GEMM: out = A(MxK) @ Bw(NxK)^T + bias, tile 128x128, BK=16, 256 thr,
// 8x8 per thread. A is chunk-local; mrow0 is the chunk's global row offset.
// EPI: 0=QKV scatter (chunk-local)  1=proj+reverse+roll+residual (global)
//      2=GELU (chunk-local)         3=add-into-out (global, MLP2 residual)
// ---------------------------------------------------------------------------
template<int EPI>
__global__ __launch_bounds__(256) void gemm_kernel(const float* __restrict__ A,
                                                   const float* __restrict__ Bw,
                                                   const float* __restrict__ bias,
                                                   float* __restrict__ out,
                                                   const float* __restrict__ resid,
                                                   int K, int mrow0)
{
    __shared__ float As[16][132];
    __shared__ float Bs[16][132];

    const int tid = threadIdx.x;
    const int m0 = blockIdx.x * 128;
    const int n0 = blockIdx.y * 128;
    const int tx = tid & 15, ty = tid >> 4;

    const int lrow = tid >> 2;             // 0..63
    const int lcg  = (tid & 3) * 4;        // 0,4,8,12

    float cc[8][8] = {};

    for (int kt = 0; kt < K; kt += 16) {
        #pragma unroll
        for (int rr = 0; rr < 2; ++rr) {
            const int r = lrow + rr * 64;
            const float4 av = *(const float4*)(A  + (size_t)(m0 + r) * K + kt + lcg);
            const float4 bv = *(const float4*)(Bw + (size_t)(n0 + r) * K + kt + lcg);
            As[lcg + 0][r] = av.x; As[lcg + 1][r] = av.y;
            As[lcg + 2][r] = av.z; As[lcg + 3][r] = av.w;
            Bs[lcg + 0][r] = bv.x; Bs[lcg + 1][r] = bv.y;
            Bs[lcg + 2][r] = bv.z; Bs[lcg + 3][r] = bv.w;
        }
        __syncthreads();
        #pragma unroll
        for (int kk = 0; kk < 16; ++kk) {
            const float4 a0 = *(const float4*)&As[kk][ty * 4];
            const float4 a1 = *(const float4*)&As[kk][ty * 4 + 64];
            const float4 b0 = *(const float4*)&Bs[kk][tx * 4];
            const float4 b1 = *(const float4*)&Bs[kk][tx * 4 + 64];
            const float ar[8] = {a0.x,a0.y,a0.z,a0.w,a1.x,a1.y,a1.z,a1.w};
            const float br[8] = {b0.x,b0.y,b0.z,b0.w,b1.x,b1.y,b1.z,b1.w};
            #pragma unroll
            for (int i = 0; i < 8; ++i)
                #pragma unroll
                for (int j = 0; j < 8; ++j)
                    cc[i][j] += ar[i] * br[j];
        }
        __syncthreads();
    }

    #pragma unroll
    for (int i = 0; i < 8; ++i) {
        const int mi = m0 + ty * 4 + (i & 3) + (i >> 2) * 64;   // chunk-local row
        if constexpr (EPI == 0) {
            const int winl = mi / NTOK;
            const int nt   = mi - winl * NTOK;
            #pragma unroll
            for (int j = 0; j < 8; ++j) {
                const int o = n0 + tx * 4 + (j & 3) + (j >> 2) * 64;
                const int sel = o >> 8, head = (o >> 5) & 7, d = o & 31;
                const size_t addr = (((size_t)(winl * 3 + sel) * 8 + head) * NTOK + nt) * HD + d;
                out[addr] = cc[i][j] + bias[o];
            }
        } else if constexpr (EPI == 1) {
            const int gmi = mrow0 + mi;
            const int win = gmi / NTOK;
            const int nt  = gmi - win * NTOK;
            const int wz = win >> 8, wh = (win >> 4) & 15, ww = win & 15;
            const int lz = nt / 72;
            const int t2 = nt - lz * 72;
            const int lh = t2 / 12, lw = t2 - lh * 12;
            const int z = (wz * 2 + lz + 1) & 7;
            int h = wh * 6 + lh + 3;  if (h >= 96)  h -= 96;
            int w = ww * 12 + lw + 6; if (w >= 192) w -= 192;
            const size_t p = ((size_t)z * 96 + h) * 192 + w;
            #pragma unroll
            for (int j = 0; j < 8; ++j) {
                const int o = n0 + tx * 4 + (j & 3) + (j >> 2) * 64;
                out[p * CDIM + o] = resid[p * CDIM + o] + cc[i][j] + bias[o];
            }
        } else if constexpr (EPI == 2) {
            #pragma unroll
            for (int j = 0; j < 8; ++j) {
                const int o = n0 + tx * 4 + (j & 3) + (j >> 2) * 64;
                const float v = cc[i][j] + bias[o];
                out[(size_t)mi * HID + o] = 0.5f * v * (1.0f + erff(v * 0.70710678118654752f));
            }
        } else {
            const int gmi = mrow0 + mi;
            #pragma unroll
            for (int j = 0; j < 8; ++j) {
                const int o = n0 + tx * 4 + (j & 3) + (j >> 2) * 64;
                out[(size_t)gmi * CDIM + o] += cc[i][j] + bias[o];
            }
        }
    }
}

// ---------------------------------------------------------------------------
extern "C" void kernel_launch(void* const* d_in, const int* in_sizes, int n_in,
                              void* d_out, int out_size, void* d_ws, size_t ws_size,
                              hipStream_t stream)
{
    const float* x     = (const float*)d_in[0];
    const float* g1    = (const float*)d_in[1];
    const float* beta1 = (const float*)d_in[2];
    const float* wqkv  = (const float*)d_in[3];
    const float* bqkv  = (const float*)d_in[4];
    const float* btab  = (const float*)d_in[5];
    const float* wproj = (const float*)d_in[6];
    const float* bproj = (const float*)d_in[7];
    const float* g2    = (const float*)d_in[8];
    const float* beta2 = (const float*)d_in[9];
    const float* w1    = (const float*)d_in[10];
    const float* b1    = (const float*)d_in[11];
    const float* w2    = (const float*)d_in[12];
    const float* b2    = (const float*)d_in[13];
    const int*   wti   = (const int*)d_in[17];
    float* out = (float*)d_out;

    // choose chunk count so scratch fits ws_size
    const size_t BIAS_ELEMS = (size_t)NHEADS * NTOK * NTOK;   // 165888
    int nch = 8;
    for (int cand : {8, 32, 128}) {
        nch = cand;
        const size_t rows = (size_t)L_TOK / cand;
        const size_t need = (BIAS_ELEMS + rows * (256 + 256 + 1024)) * 4;
        if (need <= ws_size) break;
    }
    const int wins_per = NWIN / nch;
    const int rows_per = wins_per * NTOK;     // multiple of 128 for nch in {8,32,128}

    float* rb   = (float*)d_ws;               // bias table   [8*144*144]
    float* ra   = rb + BIAS_ELEMS;            // LN out       [rows_per*256]
    float* ratt = ra + (size_t)rows_per * CDIM;   // attn out [rows_per*256]
    float* rbig = ratt + (size_t)rows_per * CDIM; // qkv/hidden [rows_per*1024]

    // dense position-bias table (once)
    bias_pre_kernel<<<(int)(BIAS_ELEMS / 256), 256, 0, stream>>>(btab, wti, rb);

    // Phase 1: LN1+shift+partition -> QKV -> attention -> proj(+reverse+roll+residual)
    for (int c = 0; c < nch; ++c) {
        const int row0 = c * rows_per;
        const int win0 = c * wins_per;
        ln_kernel<true><<<rows_per / 4, 256, 0, stream>>>(x, g1, beta1, ra, row0);
        gemm_kernel<0><<<dim3(rows_per / 128, C3 / 128), 256, 0, stream>>>(
            ra, wqkv, bqkv, rbig, nullptr, CDIM, row0);
        attn_kernel<<<wins_per * NHEADS, 192, 0, stream>>>(rbig, rb, ratt, win0);
        gemm_kernel<1><<<dim3(rows_per / 128, CDIM / 128), 256, 0, stream>>>(
            ratt, wproj, bproj, out, x, CDIM, row0);
    }

    // Phase 2: LN2 -> MLP1+GELU -> MLP2 (+= residual into d_out)
    for (int c = 0; c < nch; ++c) {
        const int row0 = c * rows_per;
        ln_kernel<false><<<rows_per / 4, 256, 0, stream>>>(out, g2, beta2, ra, row0);
        gemm_kernel<2><<<dim3(rows_per / 128, HID / 128), 256, 0, stream>>>(
            ra, w1, b1, rbig, nullptr, CDIM, row0);
        gemm_kernel<3><<<dim3(rows_per / 128, CDIM / 128), 256, 0, stream>>>(
            rbig, w2, b2, out, nullptr, HID, row0);
    }
}

// Round 4
// 1870.687 us; speedup vs baseline: 2.5478x; 2.5478x over previous
//
#include <hip/hip_runtime.h>
#include <hip/hip_bf16.h>
#include <math.h>

// Fixed instance: B=1, Z=8, H=96, W=192, C=256
#define L_TOK   147456
#define CDIM    256
#define C3      768
#define HID     1024
#define NWIN    1024
#define NTOK    144
#define NHEADS  8
#define HD      32
#define SCALE   0.1767766952966369f   // 1/sqrt(32)

typedef __attribute__((ext_vector_type(8))) short bfrag;   // 8 bf16 (4 VGPRs)
typedef __attribute__((ext_vector_type(4))) float f32x4;

__device__ __forceinline__ ushort f2bf(float f) {
    __hip_bfloat16 h = __float2bfloat16(f);
    return *reinterpret_cast<ushort*>(&h);
}
__device__ __forceinline__ float bf2f(ushort u) {
    __hip_bfloat16 h = *reinterpret_cast<__hip_bfloat16*>(&u);
    return __bfloat162float(h);
}

// window-order row gt -> spatial token index (shift + partition map; also the
// inverse scatter target for window-reverse + roll-back)
__device__ __forceinline__ int shift_src(int gt) {
    const int win = gt / NTOK;
    const int nt  = gt - win * NTOK;
    const int wz = win >> 8, wh = (win >> 4) & 15, ww = win & 15;
    const int lz = nt / 72;
    const int t2 = nt - lz * 72;
    const int lh = t2 / 12, lw = t2 - lh * 12;
    const int z = (wz * 2 + lz + 1) & 7;
    int h = wh * 6 + lh + 3;  if (h >= 96)  h -= 96;
    int w = ww * 12 + lw + 6; if (w >= 192) w -= 192;
    return (z * 96 + h) * 192 + w;
}

// ---------------------------------------------------------------------------
// Per-row LN stats: st[row] = {mean, rstd}. One wave per row.
// ---------------------------------------------------------------------------
__global__ __launch_bounds__(256) void stats_kernel(const float* __restrict__ x,
                                                    float* __restrict__ st)
{
    const int wave = threadIdx.x >> 6;
    const int lane = threadIdx.x & 63;
    const int row = blockIdx.x * 4 + wave;
    const float4 v = *(const float4*)(x + (size_t)row * CDIM + lane * 4);
    float s  = v.x + v.y + v.z + v.w;
    float ss = v.x*v.x + v.y*v.y + v.z*v.z + v.w*v.w;
    #pragma unroll
    for (int off = 32; off; off >>= 1) {
        s  += __shfl_xor(s,  off);
        ss += __shfl_xor(ss, off);
    }
    if (lane == 0) {
        const float mean = s * (1.0f / CDIM);
        const float var  = ss * (1.0f / CDIM) - mean * mean;
        st[row * 2 + 0] = mean;
        st[row * 2 + 1] = rsqrtf(var + 1e-5f);
    }
}

// ---------------------------------------------------------------------------
// fp32 -> bf16 weight convert (n divisible by 1024)
// ---------------------------------------------------------------------------
__global__ __launch_bounds__(256) void cvt_kernel(const float* __restrict__ s,
                                                  ushort* __restrict__ d)
{
    const int i = (blockIdx.x * 256 + threadIdx.x) * 4;
    const float4 v = *(const float4*)(s + i);
    d[i + 0] = f2bf(v.x); d[i + 1] = f2bf(v.y);
    d[i + 2] = f2bf(v.z); d[i + 3] = f2bf(v.w);
}

// ---------------------------------------------------------------------------
// Relative-position bias gather: bb[h][i][j] = table[posidx(i,j)][wti][h]
// ---------------------------------------------------------------------------
__global__ __launch_bounds__(256) void bias_pre_kernel(const float* __restrict__ bt,
                                                       const int* __restrict__ wti_p,
                                                       float* __restrict__ bb)
{
    const int e = blockIdx.x * 256 + threadIdx.x;        // < 8*144*144
    const int wti = *wti_p;
    const int h  = e / (NTOK * NTOK);
    const int ij = e - h * (NTOK * NTOK);
    const int i = ij / NTOK, j = ij - (ij / NTOK) * NTOK;
    const int zi = i / 72, ri = i - zi * 72, hi = ri / 12, wi = ri - (ri / 12) * 12;
    const int zj = j / 72, rj = j - zj * 72, hj = rj / 12, wj = rj - (rj / 12) * 12;
    const int idx = (zi + 2 * zj) * 828 + (hi + 6 * hj) * 23 + (wi - wj + 11);
    bb[e] = bt[((size_t)idx * 64 + wti) * 8 + h];
}

// ---------------------------------------------------------------------------
// Attention (fp32 math, bf16 I/O): one block per (local window, head).
// qkv layout (chunk-local): [(winl*3+sel)*8+head][144][32] bf16
// out layout (chunk-local): [winl*144+n][head*32+d] bf16
// ---------------------------------------------------------------------------
__global__ __launch_bounds__(192, 1) void attn_kernel(const ushort* __restrict__ qkv,
                                                      const float* __restrict__ bb,
                                                      ushort* __restrict__ outb,
                                                      int win0)
{
    __shared__ float ksh[NTOK * HD];
    __shared__ float vsh[NTOK * HD];
    __shared__ int   regs_s[NTOK];

    const int winl = blockIdx.x >> 3;
    const int win  = win0 + winl;
    const int head = blockIdx.x & 7;
    const int tid  = threadIdx.x;

    const ushort* qb = qkv + (((size_t)(winl * 3 + 0) * 8 + head) * NTOK) * HD;
    const ushort* kb = qkv + (((size_t)(winl * 3 + 1) * 8 + head) * NTOK) * HD;
    const ushort* vb = qkv + (((size_t)(winl * 3 + 2) * 8 + head) * NTOK) * HD;

    for (int i = tid; i < NTOK * HD; i += 192) {
        ksh[i] = bf2f(kb[i]);
        vsh[i] = bf2f(vb[i]);
    }
    if (tid < NTOK) {
        const int lz = tid / 72;
        const int t2 = tid - lz * 72;
        const int lh = t2 / 12, lw = t2 - lh * 12;
        const int wz = win >> 8, wh = (win >> 4) & 15, ww = win & 15;
        const int rz = (wz < 3)  ? 0 : (lz == 0 ? 1 : 2);
        const int rh = (wh < 15) ? 0 : (lh < 3  ? 1 : 2);
        const int rw = (ww < 15) ? 0 : (lw < 6  ? 1 : 2);
        regs_s[tid] = rz * 9 + rh * 3 + rw;
    }
    __syncthreads();

    if (tid < NTOK) {
        const int r = tid;
        float q[HD];
        #pragma unroll
        for (int c = 0; c < HD; ++c) q[c] = bf2f(qb[r * HD + c]) * SCALE;
        const int myreg = regs_s[r];
        const float* bb_row = bb + (size_t)head * (NTOK * NTOK) + (size_t)r * NTOK;

        float s_arr[NTOK];
        #pragma unroll
        for (int j = 0; j < NTOK; ++j) {
            float acc = 0.0f;
            #pragma unroll
            for (int c4 = 0; c4 < HD / 4; ++c4) {
                const float4 kv = *(const float4*)&ksh[j * HD + c4 * 4];
                acc += q[c4*4+0]*kv.x + q[c4*4+1]*kv.y + q[c4*4+2]*kv.z + q[c4*4+3]*kv.w;
            }
            const float m = (regs_s[j] == myreg) ? 0.0f : -100.0f;
            s_arr[j] = acc + bb_row[j] + m;
        }
        float mx = s_arr[0];
        #pragma unroll
        for (int j = 1; j < NTOK; ++j) mx = fmaxf(mx, s_arr[j]);
        float sum = 0.0f;
        #pragma unroll
        for (int j = 0; j < NTOK; ++j) { const float e = __expf(s_arr[j] - mx); s_arr[j] = e; sum += e; }
        const float inv = 1.0f / sum;

        float o[HD];
        #pragma unroll
        for (int d = 0; d < HD; ++d) o[d] = 0.0f;
        #pragma unroll
        for (int j = 0; j < NTOK; ++j) {
            const float p = s_arr[j];
            #pragma unroll
            for (int c4 = 0; c4 < HD / 4; ++c4) {
                const float4 vv = *(const float4*)&vsh[j * HD + c4 * 4];
                o[c4*4+0] += p * vv.x; o[c4*4+1] += p * vv.y;
                o[c4*4+2] += p * vv.z; o[c4*4+3] += p * vv.w;
            }
        }
        const size_t obase = ((size_t)winl * NTOK + r) * CDIM + head * HD;
        #pragma unroll
        for (int d = 0; d < HD; ++d) outb[obase + d] = f2bf(o[d] * inv);
    }
}

// ---------------------------------------------------------------------------
// bf16 MFMA GEMM: C = A(MxK) @ Bw(NxK)^T + bias. Tile 128x128, BK=32,
// 256 threads = 4 waves (2x2), each wave 4x4 frags of 16x16x32 MFMA.
// ASRC: 0 = A bf16 chunk-local rows
//       1 = A = x fp32, global rows grow0+mi, LN1 + shift-gather inline
//       2 = A = d_out fp32, global rows grow0+mi, LN2 inline
// EPI : 0 = QKV scatter (bf16, chunk-local)
//       1 = proj + window-reverse + roll + residual (fp32 -> d_out)
//       2 = GELU (bf16 -> hidden)
//       3 = += into d_out (fp32, MLP2 residual)
// ---------------------------------------------------------------------------
template<int ASRC, int EPI>
__global__ __launch_bounds__(256) void mgemm(const void* __restrict__ Ap,
                                             const ushort* __restrict__ Bw,
                                             const float* __restrict__ bias,
                                             void* __restrict__ outp,
                                             const float* __restrict__ resid,
                                             const float* __restrict__ st,
                                             const float* __restrict__ lng,
                                             const float* __restrict__ lnb,
                                             int K, int grow0)
{
    __shared__ __align__(16) ushort Asb[128][40];   // +8 pad: 80B rows (5x16B)
    __shared__ __align__(16) ushort Bsb[128][40];

    const int tid = threadIdx.x;
    const int m0 = blockIdx.x * 128;
    const int n0 = blockIdx.y * 128;
    const int w = tid >> 6, lane = tid & 63;
    const int wm = w >> 1, wn = w & 1;
    const int fr = lane & 15, kg = lane >> 4;

    // staging: thread -> (row, 16-elem half)
    const int srow  = tid >> 1;
    const int shalf = tid & 1;

    f32x4 acc[4][4];
    #pragma unroll
    for (int i = 0; i < 4; ++i)
        #pragma unroll
        for (int j = 0; j < 4; ++j)
            acc[i][j] = (f32x4){0.0f, 0.0f, 0.0f, 0.0f};

    // A-row source (fixed across K-steps)
    size_t arow_off;
    float mean = 0.0f, rstd = 0.0f;
    if constexpr (ASRC == 0) {
        arow_off = (size_t)(m0 + srow) * K;
    } else {
        const int gr  = grow0 + m0 + srow;
        const int src = (ASRC == 1) ? shift_src(gr) : gr;
        arow_off = (size_t)src * CDIM;
        mean = st[src * 2 + 0];
        rstd = st[src * 2 + 1];
    }
    const size_t brow_off = (size_t)(n0 + srow) * K;

    for (int kt = 0; kt < K; kt += 32) {
        const int c0 = kt + shalf * 16;
        // ---- stage A (16 ushorts = two uint4 per thread)
        if constexpr (ASRC == 0) {
            const ushort* A = (const ushort*)Ap;
            *(uint4*)&Asb[srow][shalf * 16]     = *(const uint4*)(A + arow_off + c0);
            *(uint4*)&Asb[srow][shalf * 16 + 8] = *(const uint4*)(A + arow_off + c0 + 8);
        } else {
            const float* A = (const float*)Ap;
            #pragma unroll
            for (int q = 0; q < 2; ++q) {
                const int c = c0 + q * 8;
                const float4 v0 = *(const float4*)(A + arow_off + c);
                const float4 v1 = *(const float4*)(A + arow_off + c + 4);
                const float4 g0 = *(const float4*)(lng + c);
                const float4 g1 = *(const float4*)(lng + c + 4);
                const float4 b0 = *(const float4*)(lnb + c);
                const float4 b1 = *(const float4*)(lnb + c + 4);
                union { ushort u[8]; uint4 q4; } pk;
                pk.u[0] = f2bf((v0.x - mean) * rstd * g0.x + b0.x);
                pk.u[1] = f2bf((v0.y - mean) * rstd * g0.y + b0.y);
                pk.u[2] = f2bf((v0.z - mean) * rstd * g0.z + b0.z);
                pk.u[3] = f2bf((v0.w - mean) * rstd * g0.w + b0.w);
                pk.u[4] = f2bf((v1.x - mean) * rstd * g1.x + b1.x);
                pk.u[5] = f2bf((v1.y - mean) * rstd * g1.y + b1.y);
                pk.u[6] = f2bf((v1.z - mean) * rstd * g1.z + b1.z);
                pk.u[7] = f2bf((v1.w - mean) * rstd * g1.w + b1.w);
                *(uint4*)&Asb[srow][shalf * 16 + q * 8] = pk.q4;
            }
        }
        // ---- stage B (16 ushorts = two uint4 per thread)
        *(uint4*)&Bsb[srow][shalf * 16]     = *(const uint4*)(Bw + brow_off + c0);
        *(uint4*)&Bsb[srow][shalf * 16 + 8] = *(const uint4*)(Bw + brow_off + c0 + 8);
        __syncthreads();

        // ---- 16 MFMA
        bfrag af[4], bfv[4];
        #pragma unroll
        for (int fm = 0; fm < 4; ++fm)
            af[fm] = *(const bfrag*)&Asb[wm * 64 + fm * 16 + fr][kg * 8];
        #pragma unroll
        for (int fn = 0; fn < 4; ++fn)
            bfv[fn] = *(const bfrag*)&Bsb[wn * 64 + fn * 16 + fr][kg * 8];
        #pragma unroll
        for (int fm = 0; fm < 4; ++fm)
            #pragma unroll
            for (int fn = 0; fn < 4; ++fn)
                acc[fm][fn] = __builtin_amdgcn_mfma_f32_16x16x32_bf16(
                    af[fm], bfv[fn], acc[fm][fn], 0, 0, 0);
        __syncthreads();
    }

    // ---- epilogue
    #pragma unroll
    for (int fn = 0; fn < 4; ++fn) {
        const int col = n0 + wn * 64 + fn * 16 + fr;
        const float bv = bias[col];
        #pragma unroll
        for (int fm = 0; fm < 4; ++fm) {
            #pragma unroll
            for (int r = 0; r < 4; ++r) {
                const int mi = m0 + wm * 64 + fm * 16 + kg * 4 + r;
                const float val = acc[fm][fn][r] + bv;
                if constexpr (EPI == 0) {
                    const int winl = mi / NTOK, nt = mi - (mi / NTOK) * NTOK;
                    const int sel = col >> 8, head = (col >> 5) & 7, d = col & 31;
                    ((ushort*)outp)[(((size_t)(winl * 3 + sel) * 8 + head) * NTOK + nt) * HD + d] = f2bf(val);
                } else if constexpr (EPI == 1) {
                    const int p = shift_src(grow0 + mi);
                    ((float*)outp)[(size_t)p * CDIM + col] = resid[(size_t)p * CDIM + col] + val;
                } else if constexpr (EPI == 2) {
                    ((ushort*)outp)[(size_t)mi * HID + col] =
                        f2bf(0.5f * val * (1.0f + erff(val * 0.70710678118654752f)));
                } else {
                    ((float*)outp)[(size_t)(grow0 + mi) * CDIM + col] += val;
                }
            }
        }
    }
}

// ---------------------------------------------------------------------------
extern "C" void kernel_launch(void* const* d_in, const int* in_sizes, int n_in,
                              void* d_out, int out_size, void* d_ws, size_t ws_size,
                              hipStream_t stream)
{
    const float* x     = (const float*)d_in[0];
    const float* g1    = (const float*)d_in[1];
    const float* beta1 = (const float*)d_in[2];
    const float* wqkv  = (const float*)d_in[3];
    const float* bqkv  = (const float*)d_in[4];
    const float* btab  = (const float*)d_in[5];
    const float* wproj = (const float*)d_in[6];
    const float* bproj = (const float*)d_in[7];
    const float* g2    = (const float*)d_in[8];
    const float* beta2 = (const float*)d_in[9];
    const float* w1    = (const float*)d_in[10];
    const float* b1    = (const float*)d_in[11];
    const float* w2    = (const float*)d_in[12];
    const float* b2    = (const float*)d_in[13];
    const int*   wti   = (const int*)d_in[17];
    float* out = (float*)d_out;

    const size_t BIAS_ELEMS = (size_t)NHEADS * NTOK * NTOK;            // 165888
    const size_t WQKV_E = (size_t)C3 * CDIM, WP_E = (size_t)CDIM * CDIM;
    const size_t W1_E = (size_t)HID * CDIM,  W2_E = (size_t)CDIM * HID;
    const size_t base_bytes = BIAS_ELEMS * 4 + (size_t)L_TOK * 4 * 4   // bias + st1 + st2
                            + (WQKV_E + WP_E + W1_E + W2_E) * 2;       // bf16 weights

    int nch = 32;
    for (int cand : {8, 16, 32}) {
        const size_t rows = (size_t)L_TOK / cand;
        if (base_bytes + rows * (CDIM + HID) * 2 <= ws_size) { nch = cand; break; }
    }
    const int wins_per = NWIN / nch;
    const int rows_per = wins_per * NTOK;      // 18432 / 9216 / 4608, all %128==0

    char* wsp = (char*)d_ws;
    float* rb  = (float*)wsp;  wsp += BIAS_ELEMS * 4;
    float* st1 = (float*)wsp;  wsp += (size_t)L_TOK * 2 * 4;
    float* st2 = (float*)wsp;  wsp += (size_t)L_TOK * 2 * 4;
    ushort* wq_b = (ushort*)wsp; wsp += WQKV_E * 2;
    ushort* wp_b = (ushort*)wsp; wsp += WP_E * 2;
    ushort* w1_b = (ushort*)wsp; wsp += W1_E * 2;
    ushort* w2_b = (ushort*)wsp; wsp += W2_E * 2;
    ushort* ratt = (ushort*)wsp; wsp += (size_t)rows_per * CDIM * 2;
    ushort* rbig = (ushort*)wsp;

    // prep: weight converts, bias table, LN1 stats
    cvt_kernel<<<(int)(WQKV_E / 1024), 256, 0, stream>>>(wqkv, wq_b);
    cvt_kernel<<<(int)(WP_E   / 1024), 256, 0, stream>>>(wproj, wp_b);
    cvt_kernel<<<(int)(W1_E   / 1024), 256, 0, stream>>>(w1, w1_b);
    cvt_kernel<<<(int)(W2_E   / 1024), 256, 0, stream>>>(w2, w2_b);
    bias_pre_kernel<<<(int)(BIAS_ELEMS / 256), 256, 0, stream>>>(btab, wti, rb);
    stats_kernel<<<L_TOK / 4, 256, 0, stream>>>(x, st1);

    // Phase 1: [LN1+shift fused] QKV -> attention -> proj(+reverse+roll+residual)
    for (int c = 0; c < nch; ++c) {
        const int row0 = c * rows_per;
        const int win0 = c * wins_per;
        mgemm<1, 0><<<dim3(rows_per / 128, C3 / 128), 256, 0, stream>>>(
            x, wq_b, bqkv, rbig, nullptr, st1, g1, beta1, CDIM, row0);
        attn_kernel<<<wins_per * NHEADS, 192, 0, stream>>>(rbig, rb, ratt, win0);
        mgemm<0, 1><<<dim3(rows_per / 128, CDIM / 128), 256, 0, stream>>>(
            ratt, wp_b, bproj, out, x, nullptr, nullptr, nullptr, CDIM, row0);
    }

    // LN2 stats over x1 (= d_out)
    stats_kernel<<<L_TOK / 4, 256, 0, stream>>>(out, st2);

    // Phase 2: [LN2 fused] MLP1+GELU -> MLP2 += residual
    for (int c = 0; c < nch; ++c) {
        const int row0 = c * rows_per;
        mgemm<2, 2><<<dim3(rows_per / 128, HID / 128), 256, 0, stream>>>(
            out, w1_b, b1, rbig, nullptr, st2, g2, beta2, CDIM, row0);
        mgemm<0, 3><<<dim3(rows_per / 128, CDIM / 128), 256, 0, stream>>>(
            rbig, w2_b, b2, out, nullptr, nullptr, nullptr, nullptr, HID, row0);
    }
}

// Round 5
// 1248.749 us; speedup vs baseline: 3.8167x; 1.4980x over previous
//
#include <hip/hip_runtime.h>
#include <hip/hip_bf16.h>
#include <math.h>

// Fixed instance: B=1, Z=8, H=96, W=192, C=256
#define L_TOK   147456
#define CDIM    256
#define C3      768
#define HID     1024
#define NWIN    1024
#define NTOK    144
#define NHEADS  8
#define HD      32
#define SCALE   0.1767766952966369f   // 1/sqrt(32)

typedef __attribute__((ext_vector_type(8))) short bfrag;   // 8 bf16 (4 VGPRs)
typedef __attribute__((ext_vector_type(4))) float f32x4;

__device__ __forceinline__ ushort f2bf(float f) {
    __hip_bfloat16 h = __float2bfloat16(f);
    return *reinterpret_cast<ushort*>(&h);
}
__device__ __forceinline__ float bf2f(ushort u) {
    __hip_bfloat16 h = *reinterpret_cast<__hip_bfloat16*>(&u);
    return __bfloat162float(h);
}

// window-order row gt -> spatial token index (shift + partition map; also the
// inverse scatter target for window-reverse + roll-back)
__device__ __forceinline__ int shift_src(int gt) {
    const int win = gt / NTOK;
    const int nt  = gt - win * NTOK;
    const int wz = win >> 8, wh = (win >> 4) & 15, ww = win & 15;
    const int lz = nt / 72;
    const int t2 = nt - lz * 72;
    const int lh = t2 / 12, lw = t2 - lh * 12;
    const int z = (wz * 2 + lz + 1) & 7;
    int h = wh * 6 + lh + 3;  if (h >= 96)  h -= 96;
    int w = ww * 12 + lw + 6; if (w >= 192) w -= 192;
    return (z * 96 + h) * 192 + w;
}

// ---------------------------------------------------------------------------
// Per-row LN stats: st[row] = {mean, rstd}. One wave per row.
// ---------------------------------------------------------------------------
__global__ __launch_bounds__(256) void stats_kernel(const float* __restrict__ x,
                                                    float* __restrict__ st)
{
    const int wave = threadIdx.x >> 6;
    const int lane = threadIdx.x & 63;
    const int row = blockIdx.x * 4 + wave;
    const float4 v = *(const float4*)(x + (size_t)row * CDIM + lane * 4);
    float s  = v.x + v.y + v.z + v.w;
    float ss = v.x*v.x + v.y*v.y + v.z*v.z + v.w*v.w;
    #pragma unroll
    for (int off = 32; off; off >>= 1) {
        s  += __shfl_xor(s,  off);
        ss += __shfl_xor(ss, off);
    }
    if (lane == 0) {
        const float mean = s * (1.0f / CDIM);
        const float var  = ss * (1.0f / CDIM) - mean * mean;
        st[row * 2 + 0] = mean;
        st[row * 2 + 1] = rsqrtf(var + 1e-5f);
    }
}

// ---------------------------------------------------------------------------
// fp32 -> bf16 weight convert (n divisible by 1024)
// ---------------------------------------------------------------------------
__global__ __launch_bounds__(256) void cvt_kernel(const float* __restrict__ s,
                                                  ushort* __restrict__ d)
{
    const int i = (blockIdx.x * 256 + threadIdx.x) * 4;
    const float4 v = *(const float4*)(s + i);
    d[i + 0] = f2bf(v.x); d[i + 1] = f2bf(v.y);
    d[i + 2] = f2bf(v.z); d[i + 3] = f2bf(v.w);
}

// ---------------------------------------------------------------------------
// Combined bias+mask table, bf16, MFMA-fragment order:
//   comb[(((cls*8+h)*9+rb)*9+ct)*256 + lane*4 + reg]
//     = bias[h][i][j] + mask(cls,i,j),  i=rb*16+(lane>>4)*4+reg, j=ct*16+(lane&15)
// cls bits: (wz==3)<<2 | (wh==15)<<1 | (ww==15)
// ---------------------------------------------------------------------------
__global__ __launch_bounds__(256) void comb_pre_kernel(const float* __restrict__ bt,
                                                       const int* __restrict__ wti_p,
                                                       ushort* __restrict__ comb)
{
    const int e = blockIdx.x * 256 + threadIdx.x;   // < 8*8*81*256 = 1327104
    const int wti = *wti_p;
    const int reg  = e & 3;
    const int lane = (e >> 2) & 63;
    const int t    = e >> 8;
    const int ct = t % 9;
    const int rb = (t / 9) % 9;
    const int h  = (t / 81) % 8;
    const int cls = t / 648;
    const int i = rb * 16 + ((lane >> 4) << 2) + reg;
    const int j = ct * 16 + (lane & 15);
    const int zi = i / 72, ri = i - zi * 72, hi = ri / 12, wi = ri - (ri / 12) * 12;
    const int zj = j / 72, rj = j - zj * 72, hj = rj / 12, wj = rj - (rj / 12) * 12;
    const int idx = (zi + 2 * zj) * 828 + (hi + 6 * hj) * 23 + (wi - wj + 11);
    const float bias = bt[((size_t)idx * 64 + wti) * 8 + h];
    const int cz = (cls >> 2) & 1, ch = (cls >> 1) & 1, cw = cls & 1;
    const int ri_ = (cz ? (zi == 0 ? 1 : 2) : 0) * 9
                  + (ch ? (hi < 3 ? 1 : 2) : 0) * 3
                  + (cw ? (wi < 6 ? 1 : 2) : 0);
    const int rj_ = (cz ? (zj == 0 ? 1 : 2) : 0) * 9
                  + (ch ? (hj < 3 ? 1 : 2) : 0) * 3
                  + (cw ? (wj < 6 ? 1 : 2) : 0);
    comb[e] = f2bf(bias + ((ri_ == rj_) ? 0.0f : -100.0f));
}

// ---------------------------------------------------------------------------
// MFMA attention: one wave per (local window, head).
// qkv layout (chunk-local): [(winl*3+sel)*8+head][144][32] bf16, Q pre-scaled.
// out layout (chunk-local): [winl*144+n][head*32+d] bf16
// Per 16-row Q block: 9 QK^T MFMAs -> frag softmax -> P via LDS -> 10 PV MFMAs.
// ---------------------------------------------------------------------------
__global__ __launch_bounds__(64) void attn_kernel(const ushort* __restrict__ qkv,
                                                  const ushort* __restrict__ comb,
                                                  ushort* __restrict__ outb,
                                                  int win0)
{
    __shared__ ushort vt[32][168];   // V^T, cols(j) padded: [144,160) zeroed
    __shared__ ushort pt[16][168];   // P tile, cols padded: [144,160) zeroed

    const int winl = blockIdx.x >> 3;
    const int head = blockIdx.x & 7;
    const int win  = win0 + winl;
    const int lane = threadIdx.x;
    const int g = lane >> 4, c = lane & 15;
    const int cls = (((win >> 8) == 3) ? 4 : 0)
                  | ((((win >> 4) & 15) == 15) ? 2 : 0)
                  | (((win & 15) == 15) ? 1 : 0);

    const ushort* qb = qkv + (((size_t)(winl * 3 + 0) * 8 + head) * NTOK) * HD;
    const ushort* kb = qkv + (((size_t)(winl * 3 + 1) * 8 + head) * NTOK) * HD;
    const ushort* vb = qkv + (((size_t)(winl * 3 + 2) * 8 + head) * NTOK) * HD;

    // zero pads
    for (int i = lane; i < 512; i += 64) vt[i >> 4][144 + (i & 15)] = 0;
    for (int i = lane; i < 256; i += 64) pt[i >> 4][144 + (i & 15)] = 0;
    // stage V transposed: vt[d][j] = V[j][d]
    for (int base = lane * 8; base < NTOK * HD; base += 512) {
        const int j = base >> 5, d0 = base & 31;
        union { ushort u[8]; uint4 q; } tv;
        tv.q = *(const uint4*)(vb + base);
        #pragma unroll
        for (int e = 0; e < 8; ++e) vt[d0 + e][j] = tv.u[e];
    }
    __syncthreads();

    // K as 9 B-fragments (col=lane&15 -> key j, k=(lane>>4)*8+e)
    bfrag kf[9];
    #pragma unroll
    for (int ct = 0; ct < 9; ++ct)
        kf[ct] = *(const bfrag*)(kb + (size_t)(ct * 16 + c) * HD + g * 8);
    // V as 2x5 B-fragments from LDS (col -> d, k -> j)
    bfrag vf[2][5];
    #pragma unroll
    for (int nt = 0; nt < 2; ++nt)
        #pragma unroll
        for (int kt = 0; kt < 5; ++kt)
            vf[nt][kt] = *(const bfrag*)&vt[nt * 16 + c][kt * 32 + g * 8];

    const ushort* cb = comb + ((size_t)cls * 8 + head) * 81 * 256;

    for (int rb = 0; rb < 9; ++rb) {
        const bfrag aq = *(const bfrag*)(qb + (size_t)(rb * 16 + c) * HD + g * 8);
        f32x4 s[9];
        #pragma unroll
        for (int ct = 0; ct < 9; ++ct)
            s[ct] = __builtin_amdgcn_mfma_f32_16x16x32_bf16(
                aq, kf[ct], (f32x4){0.0f, 0.0f, 0.0f, 0.0f}, 0, 0, 0);

        // bias + mask (fragment-ordered bf16 table, 8B coalesced per lane)
        #pragma unroll
        for (int ct = 0; ct < 9; ++ct) {
            const uint2 bw = *(const uint2*)(cb + (size_t)(rb * 9 + ct) * 256 + lane * 4);
            s[ct][0] += bf2f((ushort)(bw.x & 0xffff));
            s[ct][1] += bf2f((ushort)(bw.x >> 16));
            s[ct][2] += bf2f((ushort)(bw.y & 0xffff));
            s[ct][3] += bf2f((ushort)(bw.y >> 16));
        }

        // row softmax: rows live at (reg, lane>>4); cols split across lane&15 and ct
        float mx[4] = {-1e30f, -1e30f, -1e30f, -1e30f};
        #pragma unroll
        for (int ct = 0; ct < 9; ++ct)
            #pragma unroll
            for (int r = 0; r < 4; ++r) mx[r] = fmaxf(mx[r], s[ct][r]);
        #pragma unroll
        for (int off = 1; off < 16; off <<= 1)
            #pragma unroll
            for (int r = 0; r < 4; ++r) mx[r] = fmaxf(mx[r], __shfl_xor(mx[r], off));
        float sm[4] = {0.0f, 0.0f, 0.0f, 0.0f};
        #pragma unroll
        for (int ct = 0; ct < 9; ++ct)
            #pragma unroll
            for (int r = 0; r < 4; ++r) {
                const float e = __expf(s[ct][r] - mx[r]);
                s[ct][r] = e; sm[r] += e;
            }
        #pragma unroll
        for (int off = 1; off < 16; off <<= 1)
            #pragma unroll
            for (int r = 0; r < 4; ++r) sm[r] += __shfl_xor(sm[r], off);
        float inv[4];
        #pragma unroll
        for (int r = 0; r < 4; ++r) inv[r] = 1.0f / sm[r];

        // P (C-layout) -> LDS tile (row-major) as bf16, unnormalized
        #pragma unroll
        for (int ct = 0; ct < 9; ++ct)
            #pragma unroll
            for (int r = 0; r < 4; ++r)
                pt[g * 4 + r][ct * 16 + c] = f2bf(s[ct][r]);

        // O = P·V  (A-frags from LDS, K padded to 160)
        f32x4 o[2] = {(f32x4){0,0,0,0}, (f32x4){0,0,0,0}};
        #pragma unroll
        for (int kt = 0; kt < 5; ++kt) {
            const bfrag pa = *(const bfrag*)&pt[c][kt * 32 + g * 8];
            o[0] = __builtin_amdgcn_mfma_f32_16x16x32_bf16(pa, vf[0][kt], o[0], 0, 0, 0);
            o[1] = __builtin_amdgcn_mfma_f32_16x16x32_bf16(pa, vf[1][kt], o[1], 0, 0, 0);
        }

        // normalize rows and store
        const size_t ob = ((size_t)winl * NTOK + rb * 16 + g * 4) * CDIM + head * HD;
        #pragma unroll
        for (int nt = 0; nt < 2; ++nt)
            #pragma unroll
            for (int r = 0; r < 4; ++r)
                outb[ob + (size_t)r * CDIM + nt * 16 + c] = f2bf(o[nt][r] * inv[r]);
    }
}

// ---------------------------------------------------------------------------
// bf16 MFMA GEMM: C = A(MxK) @ Bw(NxK)^T + bias. Tile 128x128, BK=32,
// 256 threads = 4 waves (2x2), each wave 4x4 frags of 16x16x32 MFMA.
// ASRC: 0 = A bf16 chunk-local rows
//       1 = A = x fp32, global rows grow0+mi, LN1 + shift-gather inline
//       2 = A = d_out fp32, global rows grow0+mi, LN2 inline
// EPI : 0 = QKV scatter (bf16, chunk-local; Q pre-scaled by SCALE)
//       1 = proj + window-reverse + roll + residual (fp32 -> d_out)
//       2 = GELU (bf16 -> hidden)
//       3 = += into d_out (fp32, MLP2 residual)
// ---------------------------------------------------------------------------
template<int ASRC, int EPI>
__global__ __launch_bounds__(256) void mgemm(const void* __restrict__ Ap,
                                             const ushort* __restrict__ Bw,
                                             const float* __restrict__ bias,
                                             void* __restrict__ outp,
                                             const float* __restrict__ resid,
                                             const float* __restrict__ st,
                                             const float* __restrict__ lng,
                                             const float* __restrict__ lnb,
                                             int K, int grow0)
{
    __shared__ __align__(16) ushort Asb[128][40];   // +8 pad: 80B rows (5x16B)
    __shared__ __align__(16) ushort Bsb[128][40];

    const int tid = threadIdx.x;
    const int m0 = blockIdx.x * 128;
    const int n0 = blockIdx.y * 128;
    const int w = tid >> 6, lane = tid & 63;
    const int wm = w >> 1, wn = w & 1;
    const int fr = lane & 15, kg = lane >> 4;

    // staging: thread -> (row, 16-elem half)
    const int srow  = tid >> 1;
    const int shalf = tid & 1;

    f32x4 acc[4][4];
    #pragma unroll
    for (int i = 0; i < 4; ++i)
        #pragma unroll
        for (int j = 0; j < 4; ++j)
            acc[i][j] = (f32x4){0.0f, 0.0f, 0.0f, 0.0f};

    // A-row source (fixed across K-steps)
    size_t arow_off;
    float mean = 0.0f, rstd = 0.0f;
    if constexpr (ASRC == 0) {
        arow_off = (size_t)(m0 + srow) * K;
    } else {
        const int gr  = grow0 + m0 + srow;
        const int src = (ASRC == 1) ? shift_src(gr) : gr;
        arow_off = (size_t)src * CDIM;
        mean = st[src * 2 + 0];
        rstd = st[src * 2 + 1];
    }
    const size_t brow_off = (size_t)(n0 + srow) * K;

    for (int kt = 0; kt < K; kt += 32) {
        const int c0 = kt + shalf * 16;
        // ---- stage A (16 ushorts = two uint4 per thread)
        if constexpr (ASRC == 0) {
            const ushort* A = (const ushort*)Ap;
            *(uint4*)&Asb[srow][shalf * 16]     = *(const uint4*)(A + arow_off + c0);
            *(uint4*)&Asb[srow][shalf * 16 + 8] = *(const uint4*)(A + arow_off + c0 + 8);
        } else {
            const float* A = (const float*)Ap;
            #pragma unroll
            for (int q = 0; q < 2; ++q) {
                const int c = c0 + q * 8;
                const float4 v0 = *(const float4*)(A + arow_off + c);
                const float4 v1 = *(const float4*)(A + arow_off + c + 4);
                const float4 g0 = *(const float4*)(lng + c);
                const float4 g1 = *(const float4*)(lng + c + 4);
                const float4 b0 = *(const float4*)(lnb + c);
                const float4 b1 = *(const float4*)(lnb + c + 4);
                union { ushort u[8]; uint4 q4; } pk;
                pk.u[0] = f2bf((v0.x - mean) * rstd * g0.x + b0.x);
                pk.u[1] = f2bf((v0.y - mean) * rstd * g0.y + b0.y);
                pk.u[2] = f2bf((v0.z - mean) * rstd * g0.z + b0.z);
                pk.u[3] = f2bf((v0.w - mean) * rstd * g0.w + b0.w);
                pk.u[4] = f2bf((v1.x - mean) * rstd * g1.x + b1.x);
                pk.u[5] = f2bf((v1.y - mean) * rstd * g1.y + b1.y);
                pk.u[6] = f2bf((v1.z - mean) * rstd * g1.z + b1.z);
                pk.u[7] = f2bf((v1.w - mean) * rstd * g1.w + b1.w);
                *(uint4*)&Asb[srow][shalf * 16 + q * 8] = pk.q4;
            }
        }
        // ---- stage B (16 ushorts = two uint4 per thread)
        *(uint4*)&Bsb[srow][shalf * 16]     = *(const uint4*)(Bw + brow_off + c0);
        *(uint4*)&Bsb[srow][shalf * 16 + 8] = *(const uint4*)(Bw + brow_off + c0 + 8);
        __syncthreads();

        // ---- 16 MFMA
        bfrag af[4], bfv[4];
        #pragma unroll
        for (int fm = 0; fm < 4; ++fm)
            af[fm] = *(const bfrag*)&Asb[wm * 64 + fm * 16 + fr][kg * 8];
        #pragma unroll
        for (int fn = 0; fn < 4; ++fn)
            bfv[fn] = *(const bfrag*)&Bsb[wn * 64 + fn * 16 + fr][kg * 8];
        #pragma unroll
        for (int fm = 0; fm < 4; ++fm)
            #pragma unroll
            for (int fn = 0; fn < 4; ++fn)
                acc[fm][fn] = __builtin_amdgcn_mfma_f32_16x16x32_bf16(
                    af[fm], bfv[fn], acc[fm][fn], 0, 0, 0);
        __syncthreads();
    }

    // ---- epilogue
    #pragma unroll
    for (int fn = 0; fn < 4; ++fn) {
        const int col = n0 + wn * 64 + fn * 16 + fr;
        const float bv = bias[col];
        #pragma unroll
        for (int fm = 0; fm < 4; ++fm) {
            #pragma unroll
            for (int r = 0; r < 4; ++r) {
                const int mi = m0 + wm * 64 + fm * 16 + kg * 4 + r;
                float val = acc[fm][fn][r] + bv;
                if constexpr (EPI == 0) {
                    if (col < 256) val *= SCALE;   // pre-scale Q
                    const int winl = mi / NTOK, nt = mi - (mi / NTOK) * NTOK;
                    const int sel = col >> 8, head = (col >> 5) & 7, d = col & 31;
                    ((ushort*)outp)[(((size_t)(winl * 3 + sel) * 8 + head) * NTOK + nt) * HD + d] = f2bf(val);
                } else if constexpr (EPI == 1) {
                    const int p = shift_src(grow0 + mi);
                    ((float*)outp)[(size_t)p * CDIM + col] = resid[(size_t)p * CDIM + col] + val;
                } else if constexpr (EPI == 2) {
                    ((ushort*)outp)[(size_t)mi * HID + col] =
                        f2bf(0.5f * val * (1.0f + erff(val * 0.70710678118654752f)));
                } else {
                    ((float*)outp)[(size_t)(grow0 + mi) * CDIM + col] += val;
                }
            }
        }
    }
}

// ---------------------------------------------------------------------------
extern "C" void kernel_launch(void* const* d_in, const int* in_sizes, int n_in,
                              void* d_out, int out_size, void* d_ws, size_t ws_size,
                              hipStream_t stream)
{
    const float* x     = (const float*)d_in[0];
    const float* g1    = (const float*)d_in[1];
    const float* beta1 = (const float*)d_in[2];
    const float* wqkv  = (const float*)d_in[3];
    const float* bqkv  = (const float*)d_in[4];
    const float* btab  = (const float*)d_in[5];
    const float* wproj = (const float*)d_in[6];
    const float* bproj = (const float*)d_in[7];
    const float* g2    = (const float*)d_in[8];
    const float* beta2 = (const float*)d_in[9];
    const float* w1    = (const float*)d_in[10];
    const float* b1    = (const float*)d_in[11];
    const float* w2    = (const float*)d_in[12];
    const float* b2    = (const float*)d_in[13];
    const int*   wti   = (const int*)d_in[17];
    float* out = (float*)d_out;

    const size_t COMB_ELEMS = (size_t)8 * 8 * 81 * 256;                // 1327104
    const size_t WQKV_E = (size_t)C3 * CDIM, WP_E = (size_t)CDIM * CDIM;
    const size_t W1_E = (size_t)HID * CDIM,  W2_E = (size_t)CDIM * HID;
    const size_t base_bytes = COMB_ELEMS * 2 + (size_t)L_TOK * 4 * 4   // comb + st1 + st2
                            + (WQKV_E + WP_E + W1_E + W2_E) * 2;       // bf16 weights

    int nch = 32;
    for (int cand : {8, 16, 32}) {
        const size_t rows = (size_t)L_TOK / cand;
        if (base_bytes + rows * (CDIM + HID) * 2 <= ws_size) { nch = cand; break; }
    }
    const int wins_per = NWIN / nch;
    const int rows_per = wins_per * NTOK;      // 18432 / 9216 / 4608, all %128==0

    char* wsp = (char*)d_ws;
    ushort* comb = (ushort*)wsp; wsp += COMB_ELEMS * 2;
    float* st1 = (float*)wsp;  wsp += (size_t)L_TOK * 2 * 4;
    float* st2 = (float*)wsp;  wsp += (size_t)L_TOK * 2 * 4;
    ushort* wq_b = (ushort*)wsp; wsp += WQKV_E * 2;
    ushort* wp_b = (ushort*)wsp; wsp += WP_E * 2;
    ushort* w1_b = (ushort*)wsp; wsp += W1_E * 2;
    ushort* w2_b = (ushort*)wsp; wsp += W2_E * 2;
    ushort* ratt = (ushort*)wsp; wsp += (size_t)rows_per * CDIM * 2;
    ushort* rbig = (ushort*)wsp;

    // prep: weight converts, combined bias+mask table, LN1 stats
    cvt_kernel<<<(int)(WQKV_E / 1024), 256, 0, stream>>>(wqkv, wq_b);
    cvt_kernel<<<(int)(WP_E   / 1024), 256, 0, stream>>>(wproj, wp_b);
    cvt_kernel<<<(int)(W1_E   / 1024), 256, 0, stream>>>(w1, w1_b);
    cvt_kernel<<<(int)(W2_E   / 1024), 256, 0, stream>>>(w2, w2_b);
    comb_pre_kernel<<<(int)(COMB_ELEMS / 256), 256, 0, stream>>>(btab, wti, comb);
    stats_kernel<<<L_TOK / 4, 256, 0, stream>>>(x, st1);

    // Phase 1: [LN1+shift fused] QKV -> MFMA attention -> proj(+reverse+roll+residual)
    for (int c = 0; c < nch; ++c) {
        const int row0 = c * rows_per;
        const int win0 = c * wins_per;
        mgemm<1, 0><<<dim3(rows_per / 128, C3 / 128), 256, 0, stream>>>(
            x, wq_b, bqkv, rbig, nullptr, st1, g1, beta1, CDIM, row0);
        attn_kernel<<<wins_per * NHEADS, 64, 0, stream>>>(rbig, comb, ratt, win0);
        mgemm<0, 1><<<dim3(rows_per / 128, CDIM / 128), 256, 0, stream>>>(
            ratt, wp_b, bproj, out, x, nullptr, nullptr, nullptr, CDIM, row0);
    }

    // LN2 stats over x1 (= d_out)
    stats_kernel<<<L_TOK / 4, 256, 0, stream>>>(out, st2);

    // Phase 2: [LN2 fused] MLP1+GELU -> MLP2 += residual
    for (int c = 0; c < nch; ++c) {
        const int row0 = c * rows_per;
        mgemm<2, 2><<<dim3(rows_per / 128, HID / 128), 256, 0, stream>>>(
            out, w1_b, b1, rbig, nullptr, st2, g2, beta2, CDIM, row0);
        mgemm<0, 3><<<dim3(rows_per / 128, CDIM / 128), 256, 0, stream>>>(
            rbig, w2_b, b2, out, nullptr, nullptr, nullptr, nullptr, HID, row0);
    }
}